// Round 4
// baseline (343.241 us; speedup 1.0000x reference)
//
#include <hip/hip_runtime.h>
#include <hip/hip_bf16.h>
#include <stdint.h>
#include <stddef.h>

// MMD via single signed 2N x 2N RBF gram, lower triangle only.
// Round 4: barrier-free. A fragments (full K=256) register-stationary per
// 128-row strip; B fragments loaded DIRECTLY from global (L1/L2-resident Z,
// cache-line-perfect pattern: 16 rows x 64 contiguous bytes per instr).
// No LDS staging, no __syncthreads in the loop -> compiler can pipeline
// loads across k-steps and tiles; waves fully independent.

#define N_PTS   8192
#define DIM     256
#define TWO_N   16384
#define CSTRIDE 16

typedef __attribute__((ext_vector_type(8))) short short8;   // 8 x bf16
typedef __attribute__((ext_vector_type(4))) float f32x4;

// ---------------------------------------------------------------------------
// Prep: fp32 -> bf16 (row-major) + fp32 row norms + zero the output scalar.
// ---------------------------------------------------------------------------
__global__ __launch_bounds__(256) void mmd_prep(const float* __restrict__ X,
                                                const float* __restrict__ Y,
                                                __hip_bfloat16* __restrict__ Z,
                                                float* __restrict__ n2,
                                                float* __restrict__ out) {
    if (blockIdx.x == 0 && threadIdx.x == 0) out[0] = 0.0f;

    const int wave = threadIdx.x >> 6;
    const int lane = threadIdx.x & 63;
    const int row  = blockIdx.x * 4 + wave;          // 0 .. TWO_N-1

    const float* src = (row < N_PTS) ? (X + (size_t)row * DIM)
                                     : (Y + (size_t)(row - N_PTS) * DIM);
    float4 v = ((const float4*)src)[lane];           // 64 lanes x 4 = 256

    float s = v.x * v.x + v.y * v.y + v.z * v.z + v.w * v.w;
#pragma unroll
    for (int off = 32; off; off >>= 1) s += __shfl_down(s, off, 64);
    if (lane == 0) n2[row] = s;

    union { unsigned short u[4]; uint2 q; } pk;
    __hip_bfloat16 h;
    h = __float2bfloat16(v.x); pk.u[0] = *(unsigned short*)&h;
    h = __float2bfloat16(v.y); pk.u[1] = *(unsigned short*)&h;
    h = __float2bfloat16(v.z); pk.u[2] = *(unsigned short*)&h;
    h = __float2bfloat16(v.w); pk.u[3] = *(unsigned short*)&h;
    *(uint2*)((char*)Z + (size_t)row * DIM * 2 + (size_t)lane * 8) = pk.q;
}

// ---------------------------------------------------------------------------
// Main. grid = 128*16 blocks; br = 127 - (bid>>4) (heavy blocks first),
// cc = bid & 15; empty blocks (cc > br) exit.
// 4 waves; wave w owns rows [w*32, w*32+32) x all 128 cols:
// 2 (mt) x 8 (nt) MFMA tiles of 16x16x32. B frags straight from global.
// ---------------------------------------------------------------------------
__global__ __launch_bounds__(256, 2) void mmd_main(const __hip_bfloat16* __restrict__ Z,
                                                   const float* __restrict__ n2,
                                                   const int* __restrict__ sigmap,
                                                   float* __restrict__ out) {
    __shared__ float wsum[4];

    const int bid = (int)blockIdx.x;
    const int br  = 127 - (bid >> 4);
    const int cc  = bid & 15;
    if (cc > br) return;

    const int t    = threadIdx.x;
    const int wave = t >> 6;
    const int lane = t & 63;
    const int g    = lane >> 4;      // k-quad / C-row group
    const int ml   = lane & 15;
    const int rowBase = br * 128;

    const float inv_sigma = 1.0f / (float)(*sigmap);
    const float c2 = -1.4426950408889634f * inv_sigma;   // -log2e/sigma
    const float m2 = -2.0f * c2;

    // ---- A fragments (full K, 32 rows) into registers, once per block ----
    short8 af[2][8];                 // 64 VGPRs
#pragma unroll
    for (int mt = 0; mt < 2; ++mt) {
        const __hip_bfloat16* rp =
            Z + (size_t)(rowBase + wave * 32 + mt * 16 + ml) * DIM + g * 8;
#pragma unroll
        for (int kc = 0; kc < 8; ++kc)
            af[mt][kc] = *(const short8*)(rp + kc * 32);
    }
    // row-norm coefficients: a_i = c2 * |z_i|^2 for this lane's C rows
    float a_i[2][4];
#pragma unroll
    for (int mt = 0; mt < 2; ++mt)
#pragma unroll
        for (int rr = 0; rr < 4; ++rr)
            a_i[mt][rr] = c2 * n2[rowBase + wave * 32 + mt * 16 + g * 4 + rr];

    // per-lane B base: row = ml (within 16-row group), k-chunk = g
    const char* zb = (const char*)Z + (size_t)ml * (DIM * 2) + (size_t)g * 16;

    float block_acc = 0.0f;
    const int brX = (br < 64);

    for (int bc = cc; bc <= br; bc += CSTRIDE) {
        const int colBase = bc * 128;
        const char* bb = zb + (size_t)colBase * (DIM * 2);

        // column-norm coefficients for this tile
        float b_j[8];
#pragma unroll
        for (int nt = 0; nt < 8; ++nt)
            b_j[nt] = c2 * n2[colBase + nt * 16 + ml];

        f32x4 acc[2][8] = {};

        // ---- K loop: 8 steps of k=32; B frags direct from global ----
#pragma unroll
        for (int kc = 0; kc < 8; ++kc) {
            short8 bf[8];
#pragma unroll
            for (int nt = 0; nt < 8; ++nt)
                bf[nt] = *(const short8*)(bb + (size_t)nt * 16 * (DIM * 2) + kc * 64);
#pragma unroll
            for (int mt = 0; mt < 2; ++mt)
#pragma unroll
                for (int nt = 0; nt < 8; ++nt)
                    acc[mt][nt] = __builtin_amdgcn_mfma_f32_16x16x32_bf16(
                        af[mt][kc], bf[nt], acc[mt][nt], 0, 0, 0);
        }

        // ---- epilogue: sum exp2(c2*(n2i+n2j) + m2*dot), weighted ----
        float tsum = 0.0f;
#pragma unroll
        for (int mt = 0; mt < 2; ++mt)
#pragma unroll
            for (int nt = 0; nt < 8; ++nt)
#pragma unroll
                for (int rr = 0; rr < 4; ++rr)
                    tsum += __builtin_amdgcn_exp2f(
                        fmaf(acc[mt][nt][rr], m2, a_i[mt][rr] + b_j[nt]));

        const float sgn = ((bc < 64) == brX) ? 1.0f : -1.0f;
        const float w   = (bc == br) ? sgn : 2.0f * sgn;   // symmetry weight
        block_acc = fmaf(w, tsum, block_acc);
    }

    // ---- block reduction + single atomic ----
    float s = block_acc;
#pragma unroll
    for (int off = 32; off; off >>= 1) s += __shfl_down(s, off, 64);
    if (lane == 0) wsum[wave] = s;
    __syncthreads();
    if (t == 0)
        atomicAdd(out, (wsum[0] + wsum[1] + wsum[2] + wsum[3]) * (1.0f / 67108864.0f));
}

// ---------------------------------------------------------------------------
extern "C" void kernel_launch(void* const* d_in, const int* in_sizes, int n_in,
                              void* d_out, int out_size, void* d_ws, size_t ws_size,
                              hipStream_t stream) {
    const float* X      = (const float*)d_in[0];
    const float* Y      = (const float*)d_in[1];
    const int*   sigmap = (const int*)d_in[2];
    float*       out    = (float*)d_out;

    __hip_bfloat16* Z  = (__hip_bfloat16*)d_ws;                       // 8 MB
    float*          n2 = (float*)((char*)d_ws + (size_t)TWO_N * DIM * 2);

    mmd_prep<<<TWO_N / 4, 256, 0, stream>>>(X, Y, Z, n2, out);
    mmd_main<<<128 * CSTRIDE, 256, 0, stream>>>(Z, n2, sigmap, out);
}

// Round 5
// 168.356 us; speedup vs baseline: 2.0388x; 2.0388x over previous
//
#include <hip/hip_runtime.h>
#include <hip/hip_bf16.h>
#include <stdint.h>
#include <stddef.h>

// MMD via single signed 2N x 2N RBF gram, lower triangle only.
// Round 5: back to LDS staging (r4's direct-global was latency-bound, 9% util).
// 2x2 wave tiling (64x64 per wave) halves per-wave B LDS reads vs r3's 4x1
// (the measured ~40us LDS-read pipe). r2 tried this and spilled (~62MB scratch);
// this version shaves ~20 regs to fit 256: row norms live in LDS (read as
// f32x4 in epilogue), col norms read from L1-hot global in epilogue, norms
// pre-scaled by c2 = -log2e/sigma in prep.

#define N_PTS   8192
#define DIM     256
#define TWO_N   16384
#define CSTRIDE 16

#define AS1 __attribute__((address_space(1)))
#define AS3 __attribute__((address_space(3)))

typedef __attribute__((ext_vector_type(8))) short short8;   // 8 x bf16
typedef __attribute__((ext_vector_type(4))) float f32x4;

// ---------------------------------------------------------------------------
// Prep: fp32 -> bf16 (row-major) + c2-scaled fp32 row norms + zero output.
// n2[row] = c2 * |z_row|^2 with c2 = -log2e/sigma (epilogue adds directly).
// ---------------------------------------------------------------------------
__global__ __launch_bounds__(256) void mmd_prep(const float* __restrict__ X,
                                                const float* __restrict__ Y,
                                                const int* __restrict__ sigmap,
                                                __hip_bfloat16* __restrict__ Z,
                                                float* __restrict__ n2,
                                                float* __restrict__ out) {
    if (blockIdx.x == 0 && threadIdx.x == 0) out[0] = 0.0f;

    const int wave = threadIdx.x >> 6;
    const int lane = threadIdx.x & 63;
    const int row  = blockIdx.x * 4 + wave;          // 0 .. TWO_N-1

    const float* src = (row < N_PTS) ? (X + (size_t)row * DIM)
                                     : (Y + (size_t)(row - N_PTS) * DIM);
    float4 v = ((const float4*)src)[lane];           // 64 lanes x 4 = 256

    float s = v.x * v.x + v.y * v.y + v.z * v.z + v.w * v.w;
#pragma unroll
    for (int off = 32; off; off >>= 1) s += __shfl_down(s, off, 64);
    if (lane == 0) {
        const float c2 = -1.4426950408889634f / (float)(*sigmap);
        n2[row] = c2 * s;
    }

    union { unsigned short u[4]; uint2 q; } pk;
    __hip_bfloat16 h;
    h = __float2bfloat16(v.x); pk.u[0] = *(unsigned short*)&h;
    h = __float2bfloat16(v.y); pk.u[1] = *(unsigned short*)&h;
    h = __float2bfloat16(v.z); pk.u[2] = *(unsigned short*)&h;
    h = __float2bfloat16(v.w); pk.u[3] = *(unsigned short*)&h;
    *(uint2*)((char*)Z + (size_t)row * DIM * 2 + (size_t)lane * 8) = pk.q;
}

// ---------------------------------------------------------------------------
// Main. grid = 128*16; br = 127 - (bid>>4) (heavy blocks first), cc = bid&15.
// 4 waves in 2x2: wave (wm,wn) owns 64x64 of the 128x128 tile = 4x4 MFMA
// tiles of 16x16x32. A frags (full K=256) register-stationary; B streams
// through 64 KB LDS in two software-pipelined 32 KB k-halves.
// ---------------------------------------------------------------------------
__global__ __launch_bounds__(256, 2) void mmd_main(const __hip_bfloat16* __restrict__ Z,
                                                   const float* __restrict__ n2,
                                                   const int* __restrict__ sigmap,
                                                   float* __restrict__ out) {
    __shared__ short8 bsm[4096];    // [2 k-halves][128 cols][16 chunks], XOR swizzle
    __shared__ float n2rS[128];     // c2*|z|^2 for this block's 128 rows
    __shared__ float wsum[4];

    const int bid = (int)blockIdx.x;
    const int br  = 127 - (bid >> 4);
    const int cc  = bid & 15;
    if (cc > br) return;

    const int t    = threadIdx.x;
    const int wave = t >> 6;
    const int lane = t & 63;
    const int wm   = wave >> 1;
    const int wn   = wave & 1;
    const int g    = lane >> 4;
    const int ml   = lane & 15;
    const int rowBase = br * 128;

    const float m2 = 2.8853900817779268f / (float)(*sigmap);   // -2*c2

    char* smem_b = (char*)bsm;

    // ---- stage B k-half 0 of FIRST tile (overlaps A-frag loads below) ----
    {
        const int colBase0 = cc * 128;
#pragma unroll
        for (int i = 0; i < 8; ++i) {
            const int cidx = i * 256 + t;            // 0..2047
            const int row  = cidx >> 4;              // col index j
            const int s    = cidx & 15;              // LDS chunk slot
            const int gc   = s ^ (row & 7);          // XOR swizzle on source
            const __hip_bfloat16* gp = Z + (size_t)(colBase0 + row) * DIM + gc * 8;
            __builtin_amdgcn_global_load_lds((const AS1 void*)gp,
                                             (AS3 void*)(smem_b + (size_t)cidx * 16), 16, 0, 0);
        }
    }
    // row norms into LDS (consumed in epilogue, after first sync)
    if (t < 128) n2rS[t] = n2[rowBase + t];

    // ---- A fragments (full K, 64 rows of this wave) into registers ----
    short8 af[4][8];                 // 128 VGPRs
#pragma unroll
    for (int mt = 0; mt < 4; ++mt) {
        const __hip_bfloat16* rp =
            Z + (size_t)(rowBase + wm * 64 + mt * 16 + ml) * DIM + g * 8;
#pragma unroll
        for (int kc = 0; kc < 8; ++kc)
            af[mt][kc] = *(const short8*)(rp + kc * 32);
    }

    float block_acc = 0.0f;
    const int brX = (br < 64);

    for (int bc = cc; bc <= br; bc += CSTRIDE) {
        const int colBase = bc * 128;

        f32x4 acc[4][4] = {};

        __syncthreads();                 // k-half0 of this tile landed

        // ---- stage k-half 1 (overlaps h0 compute) ----
#pragma unroll
        for (int i = 0; i < 8; ++i) {
            const int cidx = i * 256 + t;
            const int row  = cidx >> 4;
            const int s    = cidx & 15;
            const int gc   = s ^ (row & 7);
            const __hip_bfloat16* gp = Z + (size_t)(colBase + row) * DIM + 128 + gc * 8;
            __builtin_amdgcn_global_load_lds((const AS1 void*)gp,
                                             (AS3 void*)(smem_b + 32768 + (size_t)cidx * 16), 16, 0, 0);
        }

        // ---- compute k-half 0 ----
#pragma unroll
        for (int kc2 = 0; kc2 < 4; ++kc2) {
            const int j = kc2 * 4 + g;
            short8 bf[4];
#pragma unroll
            for (int nt = 0; nt < 4; ++nt) {
                const int rz = wn * 64 + nt * 16 + ml;
                bf[nt] = bsm[rz * 16 + (j ^ (rz & 7))];
            }
#pragma unroll
            for (int mt = 0; mt < 4; ++mt)
#pragma unroll
                for (int nt = 0; nt < 4; ++nt)
                    acc[mt][nt] = __builtin_amdgcn_mfma_f32_16x16x32_bf16(
                        af[mt][kc2], bf[nt], acc[mt][nt], 0, 0, 0);
        }

        __syncthreads();                 // k-half1 landed; all done reading h0

        // ---- stage k-half 0 of NEXT tile (overlaps h1 compute + epilogue) ----
        if (bc + CSTRIDE <= br) {
            const int colBaseN = colBase + CSTRIDE * 128;
#pragma unroll
            for (int i = 0; i < 8; ++i) {
                const int cidx = i * 256 + t;
                const int row  = cidx >> 4;
                const int s    = cidx & 15;
                const int gc   = s ^ (row & 7);
                const __hip_bfloat16* gp = Z + (size_t)(colBaseN + row) * DIM + gc * 8;
                __builtin_amdgcn_global_load_lds((const AS1 void*)gp,
                                                 (AS3 void*)(smem_b + (size_t)cidx * 16), 16, 0, 0);
            }
        }

        // ---- compute k-half 1 ----
#pragma unroll
        for (int kc2 = 0; kc2 < 4; ++kc2) {
            const int j = kc2 * 4 + g;
            short8 bf[4];
#pragma unroll
            for (int nt = 0; nt < 4; ++nt) {
                const int rz = wn * 64 + nt * 16 + ml;
                bf[nt] = bsm[2048 + rz * 16 + (j ^ (rz & 7))];
            }
#pragma unroll
            for (int mt = 0; mt < 4; ++mt)
#pragma unroll
                for (int nt = 0; nt < 4; ++nt)
                    acc[mt][nt] = __builtin_amdgcn_mfma_f32_16x16x32_bf16(
                        af[mt][4 + kc2], bf[nt], acc[mt][nt], 0, 0, 0);
        }

        // ---- epilogue: sum exp2((c2 n2i) + (c2 n2j) + m2*dot), weighted ----
        float tsum = 0.0f;
#pragma unroll
        for (int nt = 0; nt < 4; ++nt) {
            const float bj = n2[colBase + wn * 64 + nt * 16 + ml];  // L1-hot
#pragma unroll
            for (int mt = 0; mt < 4; ++mt) {
                const f32x4 ar = *(const f32x4*)&n2rS[wm * 64 + mt * 16 + g * 4];
#pragma unroll
                for (int rr = 0; rr < 4; ++rr)
                    tsum += __builtin_amdgcn_exp2f(
                        fmaf(acc[mt][nt][rr], m2, ar[rr] + bj));
            }
        }

        const float sgn = ((bc < 64) == brX) ? 1.0f : -1.0f;
        const float w   = (bc == br) ? sgn : 2.0f * sgn;   // symmetry weight
        block_acc = fmaf(w, tsum, block_acc);
    }

    // ---- block reduction + single atomic ----
    float s = block_acc;
#pragma unroll
    for (int off = 32; off; off >>= 1) s += __shfl_down(s, off, 64);
    if (lane == 0) wsum[wave] = s;
    __syncthreads();
    if (t == 0)
        atomicAdd(out, (wsum[0] + wsum[1] + wsum[2] + wsum[3]) * (1.0f / 67108864.0f));
}

// ---------------------------------------------------------------------------
extern "C" void kernel_launch(void* const* d_in, const int* in_sizes, int n_in,
                              void* d_out, int out_size, void* d_ws, size_t ws_size,
                              hipStream_t stream) {
    const float* X      = (const float*)d_in[0];
    const float* Y      = (const float*)d_in[1];
    const int*   sigmap = (const int*)d_in[2];
    float*       out    = (float*)d_out;

    __hip_bfloat16* Z  = (__hip_bfloat16*)d_ws;                       // 8 MB
    float*          n2 = (float*)((char*)d_ws + (size_t)TWO_N * DIM * 2);

    mmd_prep<<<TWO_N / 4, 256, 0, stream>>>(X, Y, sigmap, Z, n2, out);
    mmd_main<<<128 * CSTRIDE, 256, 0, stream>>>(Z, n2, sigmap, out);
}

// Round 6
// 141.499 us; speedup vs baseline: 2.4258x; 1.1898x over previous
//
#include <hip/hip_runtime.h>
#include <hip/hip_bf16.h>
#include <stdint.h>
#include <stddef.h>

// MMD via single signed 2N x 2N RBF gram, lower triangle only.
// Round 6: fp8 e4m3. 2-reg MFMA operands make the 2x2 (64x64/wave) tiling fit
// in registers (af 64 + acc 64 + misc ~50 < 256; bf16 2x2 spilled twice).
// Full 32 KB B tile double-buffered in 64 KB LDS -> 1 barrier/tile.
// Full-16 XOR swizzle kills the residual bank conflicts (r3/r5: tilesx1024/512
// conflict cycles from the &7-only swizzle).

#define N_PTS   8192
#define DIM     256
#define TWO_N   16384
#define CSTRIDE 16

#define AS1 __attribute__((address_space(1)))
#define AS3 __attribute__((address_space(3)))

typedef __attribute__((ext_vector_type(4))) float f32x4;

// ---------------------------------------------------------------------------
// Prep: fp32 -> fp8 e4m3 (row-major, RNE via v_cvt_pk_fp8_f32) +
// c2-scaled fp32 row norms (c2 = -log2e/sigma) + zero output scalar.
// ---------------------------------------------------------------------------
__global__ __launch_bounds__(256) void mmd_prep(const float* __restrict__ X,
                                                const float* __restrict__ Y,
                                                const int* __restrict__ sigmap,
                                                unsigned char* __restrict__ Zf8,
                                                float* __restrict__ n2,
                                                float* __restrict__ out) {
    if (blockIdx.x == 0 && threadIdx.x == 0) out[0] = 0.0f;

    const int wave = threadIdx.x >> 6;
    const int lane = threadIdx.x & 63;
    const int row  = blockIdx.x * 4 + wave;          // 0 .. TWO_N-1

    const float* src = (row < N_PTS) ? (X + (size_t)row * DIM)
                                     : (Y + (size_t)(row - N_PTS) * DIM);
    float4 v = ((const float4*)src)[lane];           // 64 lanes x 4 = 256

    float s = v.x * v.x + v.y * v.y + v.z * v.z + v.w * v.w;
#pragma unroll
    for (int off = 32; off; off >>= 1) s += __shfl_down(s, off, 64);
    if (lane == 0) {
        const float c2 = -1.4426950408889634f / (float)(*sigmap);
        n2[row] = c2 * s;                            // pre-scaled: epilogue adds directly
    }

    const int p01 = __builtin_amdgcn_cvt_pk_fp8_f32(v.x, v.y, 0, false);
    const int p23 = __builtin_amdgcn_cvt_pk_fp8_f32(v.z, v.w, 0, false);
    const unsigned int pk = ((unsigned)p01 & 0xffffu) | ((unsigned)p23 << 16);
    *(unsigned int*)(Zf8 + (size_t)row * DIM + (size_t)lane * 4) = pk;
}

// ---------------------------------------------------------------------------
// Main. grid = 128*16; br = 127 - (bid>>4) (heavy blocks first), cc = bid&15;
// empty blocks (cc > br) exit. 4 waves in 2x2: wave (wm,wn) owns 64x64 of the
// 128x128 tile = 4x4 MFMA tiles of 16x16x32 fp8. A frags (full K=256)
// register-stationary (64 VGPRs); B tiles (32 KB fp8) double-buffered in LDS.
// ---------------------------------------------------------------------------
__global__ __launch_bounds__(256, 2) void mmd_main(const unsigned char* __restrict__ Zf8,
                                                   const float* __restrict__ n2,
                                                   const int* __restrict__ sigmap,
                                                   float* __restrict__ out) {
    __shared__ char smem_b[65536];   // 2 x 32 KB B-tile buffers, 16B-slot XOR swizzle
    __shared__ float wsum[4];

    const int bid = (int)blockIdx.x;
    const int br  = 127 - (bid >> 4);
    const int cc  = bid & 15;
    if (cc > br) return;

    const int t    = threadIdx.x;
    const int wave = t >> 6;
    const int lane = t & 63;
    const int wm   = wave >> 1;
    const int wn   = wave & 1;
    const int g    = lane >> 4;      // k-quad
    const int ml   = lane & 15;
    const int rowBase = br * 128;

    const float m2 = 2.8853900817779268f / (float)(*sigmap);   // -2*c2 = 2*log2e/sigma

    // ---- stage B tile 0 into buffer 0 (overlaps A-frag loads below) ----
    {
        const int colBase0 = cc * 128;
#pragma unroll
        for (int i = 0; i < 8; ++i) {
            const int cidx = i * 256 + t;            // 0..2047 16B-chunks
            const int col  = cidx >> 4;              // col 0..127
            const int s    = cidx & 15;              // LDS slot
            const int gc   = s ^ (col & 15);         // XOR swizzle on source chunk
            const unsigned char* gp = Zf8 + (size_t)(colBase0 + col) * DIM + gc * 16;
            __builtin_amdgcn_global_load_lds((const AS1 void*)gp,
                                             (AS3 void*)(smem_b + (size_t)cidx * 16), 16, 0, 0);
        }
    }

    // ---- A fragments (full K, this wave's 64 rows) into registers ----
    long af[4][8];                   // 64 VGPRs
#pragma unroll
    for (int mt = 0; mt < 4; ++mt) {
        const unsigned char* rp =
            Zf8 + (size_t)(rowBase + wm * 64 + mt * 16 + ml) * DIM + g * 8;
#pragma unroll
        for (int kc = 0; kc < 8; ++kc)
            af[mt][kc] = *(const long*)(rp + kc * 32);
    }
    // row-norm coefficients (already c2-scaled): this lane's 16 C rows
    float a_i[4][4];
#pragma unroll
    for (int mt = 0; mt < 4; ++mt)
#pragma unroll
        for (int rr = 0; rr < 4; ++rr)
            a_i[mt][rr] = n2[rowBase + wm * 64 + mt * 16 + g * 4 + rr];

    float block_acc = 0.0f;
    const int brX = (br < 64);
    int cur = 0;

    for (int bc = cc; bc <= br; bc += CSTRIDE) {
        const int colBase = bc * 128;

        // col-norm coefficients for this tile (L1-hot global)
        float b_j[4];
#pragma unroll
        for (int nt = 0; nt < 4; ++nt)
            b_j[nt] = n2[colBase + wn * 64 + nt * 16 + ml];

        f32x4 acc[4][4] = {};

        __syncthreads();             // current buffer staged; other buffer free

        // ---- stage NEXT tile into the other buffer (overlaps compute) ----
        if (bc + CSTRIDE <= br) {
            const int colBaseN = colBase + CSTRIDE * 128;
            char* dst = smem_b + (cur ^ 1) * 32768;
#pragma unroll
            for (int i = 0; i < 8; ++i) {
                const int cidx = i * 256 + t;
                const int col  = cidx >> 4;
                const int s    = cidx & 15;
                const int gc   = s ^ (col & 15);
                const unsigned char* gp = Zf8 + (size_t)(colBaseN + col) * DIM + gc * 16;
                __builtin_amdgcn_global_load_lds((const AS1 void*)gp,
                                                 (AS3 void*)(dst + (size_t)cidx * 16), 16, 0, 0);
            }
        }

        // ---- compute: 8 k-steps of K=32 ----
        const char* buf = smem_b + cur * 32768;
#pragma unroll
        for (int kc = 0; kc < 8; ++kc) {
            const int jp   = kc * 2 + (g >> 1);      // 16B slot index of chunk j=kc*4+g
            const int half = (g & 1) * 8;
            long bf[4];
#pragma unroll
            for (int nt = 0; nt < 4; ++nt) {
                const int col = wn * 64 + nt * 16 + ml;
                bf[nt] = *(const long*)(buf + (size_t)col * 256
                                            + (size_t)(jp ^ (col & 15)) * 16 + half);
            }
#pragma unroll
            for (int mt = 0; mt < 4; ++mt)
#pragma unroll
                for (int nt = 0; nt < 4; ++nt)
                    acc[mt][nt] = __builtin_amdgcn_mfma_f32_16x16x32_fp8_fp8(
                        af[mt][kc], bf[nt], acc[mt][nt], 0, 0, 0);
        }

        // ---- epilogue: sum exp2(c2*n2i + c2*n2j + m2*dot), weighted ----
        float tsum = 0.0f;
#pragma unroll
        for (int mt = 0; mt < 4; ++mt)
#pragma unroll
            for (int nt = 0; nt < 4; ++nt) {
                const float ab = b_j[nt];
#pragma unroll
                for (int rr = 0; rr < 4; ++rr)
                    tsum += __builtin_amdgcn_exp2f(
                        fmaf(acc[mt][nt][rr], m2, a_i[mt][rr] + ab));
            }

        const float sgn = ((bc < 64) == brX) ? 1.0f : -1.0f;
        const float w   = (bc == br) ? sgn : 2.0f * sgn;   // symmetry weight
        block_acc = fmaf(w, tsum, block_acc);
        cur ^= 1;
    }

    // ---- block reduction + single atomic ----
    float s = block_acc;
#pragma unroll
    for (int off = 32; off; off >>= 1) s += __shfl_down(s, off, 64);
    if (lane == 0) wsum[wave] = s;
    __syncthreads();
    if (t == 0)
        atomicAdd(out, (wsum[0] + wsum[1] + wsum[2] + wsum[3]) * (1.0f / 67108864.0f));
}

// ---------------------------------------------------------------------------
extern "C" void kernel_launch(void* const* d_in, const int* in_sizes, int n_in,
                              void* d_out, int out_size, void* d_ws, size_t ws_size,
                              hipStream_t stream) {
    const float* X      = (const float*)d_in[0];
    const float* Y      = (const float*)d_in[1];
    const int*   sigmap = (const int*)d_in[2];
    float*       out    = (float*)d_out;

    unsigned char* Zf8 = (unsigned char*)d_ws;                        // 4 MB
    float*         n2  = (float*)((char*)d_ws + (size_t)TWO_N * DIM);

    mmd_prep<<<TWO_N / 4, 256, 0, stream>>>(X, Y, sigmap, Zf8, n2, out);
    mmd_main<<<128 * CSTRIDE, 256, 0, stream>>>(Zf8, n2, sigmap, out);
}